// Round 14
// baseline (410.226 us; speedup 1.0000x reference)
//
#include <hip/hip_runtime.h>
#include <hip/hip_bf16.h>

#define CH 8
#define SEC 32768
#define FIN 64
#define FOUT 64
#define UN 512
#define BM 256   // 8 waves x 32 rows per wave

typedef __bf16 bf16;
typedef bf16 bf16x8 __attribute__((ext_vector_type(8)));
typedef float f32x4 __attribute__((ext_vector_type(4)));
typedef float f32x16 __attribute__((ext_vector_type(16)));

// async global->LDS, 16B/lane; LDS dest = wave-uniform base + lane*16
__device__ __forceinline__ void gload_lds16(const void* g, void* l) {
  __builtin_amdgcn_global_load_lds(
      (const __attribute__((address_space(1))) void*)g,
      (__attribute__((address_space(3))) void*)l, 16, 0, 0);
}

// 8 consecutive fp32 -> bf16x8
__device__ __forceinline__ bf16x8 cvt8(const float* __restrict__ src) {
  f32x4 u0 = *(const f32x4*)src;
  f32x4 u1 = *(const f32x4*)(src + 4);
  bf16x8 v;
  v[0] = (bf16)u0[0]; v[1] = (bf16)u0[1]; v[2] = (bf16)u0[2]; v[3] = (bf16)u0[3];
  v[4] = (bf16)u1[0]; v[5] = (bf16)u1[1]; v[6] = (bf16)u1[2]; v[7] = (bf16)u1[3];
  return v;
}

// two f32x4 runs at src and src+8 (the kappa^-1 gather) -> bf16x8
__device__ __forceinline__ bf16x8 cvt8_gap(const float* __restrict__ src) {
  f32x4 u0 = *(const f32x4*)src;
  f32x4 u1 = *(const f32x4*)(src + 8);
  bf16x8 v;
  v[0] = (bf16)u0[0]; v[1] = (bf16)u0[1]; v[2] = (bf16)u0[2]; v[3] = (bf16)u0[3];
  v[4] = (bf16)u1[0]; v[5] = (bf16)u1[1]; v[6] = (bf16)u1[2]; v[7] = (bf16)u1[3];
  return v;
}

// ---------------------------------------------------------------------------
// Register-resident MLP. Wave owns 32 rows for ALL layers; activations live
// in bf16x8 register banks (lane (m=l&31, hi=l>>5), frag j holds k-positions
// j*16+hi*8..+7 of row m). D of mfma(W,X) keeps the row on the same lane:
// col=m=lane&31, n-slot s=(reg&3)+8*(reg>>2)+4*hi. The slot->k permutation
// kappa (s -> (s&3)+((s>>3)&1)*4+((s>>2)&1)*8+(s>>4)*16) is absorbed into the
// weight pre-swizzle, so acc regs 0..7 / 8..15 (after bias+relu+cvt) ARE the
// next layer's frags for ksteps 2t / 2t+1 (t = c*2+nt). No act LDS, no
// cross-lane ops. LDS only broadcasts weight chunks (64 feats x K = 64KB at
// K=512), double-buffered halves, staged cooperatively via global_load_lds.
// ---------------------------------------------------------------------------
template<int K, bool WSPATH>
__device__ __forceinline__ void run_hidden(
    const bf16* __restrict__ wc,    // channel's swizzled layer weights
    const float* __restrict__ wfc,  // raw fp32 fallback
    const float* __restrict__ bias,
    const bf16x8 (&Ain)[K / 16], bf16x8 (&Aout)[32],
    char* __restrict__ lds, int tid, int l, int l31, int hi)
{
  constexpr int NKS = K / 16;

  if constexpr (WSPATH) {
    __syncthreads();   // prior LDS readers done before we overwrite
#pragma unroll
    for (int i = 0; i < 8; ++i)   // K=512: chunk0 (64KB); K=64: WHOLE layer
      gload_lds16((const char*)wc + tid * 16 + i * 8192,
                  lds + tid * 16 + i * 8192);
    __syncthreads();
  }

#pragma unroll
  for (int c = 0; c < 8; ++c) {
    const char* wb = lds;
    if constexpr (WSPATH) {
      if constexpr (K == 64) {
        wb = lds + c * 8192 + l * 16;
      } else {
        if (c + 1 < 8) {  // prefetch next chunk into other half
          const char* src = (const char*)wc + (size_t)(c + 1) * 65536;
#pragma unroll
          for (int i = 0; i < 8; ++i)
            gload_lds16(src + tid * 16 + i * 8192,
                        lds + ((c + 1) & 1) * 65536 + tid * 16 + i * 8192);
        }
        wb = lds + (c & 1) * 65536 + l * 16;
      }
    }

    f32x16 acc0, acc1;
#pragma unroll
    for (int r = 0; r < 16; ++r) { acc0[r] = 0.f; acc1[r] = 0.f; }

#pragma unroll
    for (int j = 0; j < NKS; ++j) {
      bf16x8 b0, b1;
      if constexpr (WSPATH) {
        b0 = *(const bf16x8*)(wb + (0 * NKS + j) * 1024);
        b1 = *(const bf16x8*)(wb + (1 * NKS + j) * 1024);
      } else {
        const int r0 = c * 64 + l31;
        if constexpr (K == 64) {
          b0 = cvt8(wfc + (size_t)r0 * K + j * 16 + hi * 8);
          b1 = cvt8(wfc + (size_t)(r0 + 32) * K + j * 16 + hi * 8);
        } else {
          const int coff = (j >> 1) * 32 + (j & 1) * 16 + hi * 4;
          b0 = cvt8_gap(wfc + (size_t)r0 * K + coff);
          b1 = cvt8_gap(wfc + (size_t)(r0 + 32) * K + coff);
        }
      }
      acc0 = __builtin_amdgcn_mfma_f32_32x32x16_bf16(b0, Ain[j], acc0, 0, 0, 0);
      acc1 = __builtin_amdgcn_mfma_f32_32x32x16_bf16(b1, Ain[j], acc1, 0, 0, 0);
    }

    // bias + relu + repack: regs 0..7 -> kstep 2t, regs 8..15 -> kstep 2t+1
#pragma unroll
    for (int nt = 0; nt < 2; ++nt) {
      const f32x16 A = (nt == 0) ? acc0 : acc1;
      float v[16];
#pragma unroll
      for (int q = 0; q < 4; ++q) {
        const f32x4 bv = *(const f32x4*)(bias + c * 64 + nt * 32 + q * 8 + hi * 4);
#pragma unroll
        for (int r = 0; r < 4; ++r) {
          const float t = A[q * 4 + r] + bv[r];
          v[q * 4 + r] = t > 0.f ? t : 0.f;
        }
      }
      bf16x8 p0, p1;
#pragma unroll
      for (int e = 0; e < 8; ++e) { p0[e] = (bf16)v[e]; p1[e] = (bf16)v[8 + e]; }
      Aout[(c * 2 + nt) * 2 + 0] = p0;
      Aout[(c * 2 + nt) * 2 + 1] = p1;
    }

    if constexpr (WSPATH && K != 64) __syncthreads();  // prefetch landed; half free
  }
}

// ---------------------------------------------------------------------------
// Final layer: one 64-feature chunk, K=512, no relu, fp32 store. Lane holds
// row m and 4-consecutive-col quads -> f32x4 stores.
// ---------------------------------------------------------------------------
template<bool WSPATH>
__device__ __forceinline__ void run_final(
    const bf16* __restrict__ wc, const float* __restrict__ wfc,
    const float* __restrict__ bias, const bf16x8 (&Ain)[32],
    float* __restrict__ grow,   // out + myrow*FOUT
    char* __restrict__ lds, int tid, int l, int l31, int hi)
{
  if constexpr (WSPATH) {
    __syncthreads();
#pragma unroll
    for (int i = 0; i < 8; ++i)
      gload_lds16((const char*)wc + tid * 16 + i * 8192, lds + tid * 16 + i * 8192);
    __syncthreads();
  }

  f32x16 acc0, acc1;
#pragma unroll
  for (int r = 0; r < 16; ++r) { acc0[r] = 0.f; acc1[r] = 0.f; }

#pragma unroll
  for (int j = 0; j < 32; ++j) {
    bf16x8 b0, b1;
    if constexpr (WSPATH) {
      b0 = *(const bf16x8*)(lds + (j) * 1024 + l * 16);
      b1 = *(const bf16x8*)(lds + (32 + j) * 1024 + l * 16);
    } else {
      const int coff = (j >> 1) * 32 + (j & 1) * 16 + hi * 4;
      b0 = cvt8_gap(wfc + (size_t)l31 * UN + coff);
      b1 = cvt8_gap(wfc + (size_t)(32 + l31) * UN + coff);
    }
    acc0 = __builtin_amdgcn_mfma_f32_32x32x16_bf16(b0, Ain[j], acc0, 0, 0, 0);
    acc1 = __builtin_amdgcn_mfma_f32_32x32x16_bf16(b1, Ain[j], acc1, 0, 0, 0);
  }

#pragma unroll
  for (int nt = 0; nt < 2; ++nt) {
    const f32x16 A = (nt == 0) ? acc0 : acc1;
#pragma unroll
    for (int q = 0; q < 4; ++q) {
      const f32x4 bv = *(const f32x4*)(bias + nt * 32 + q * 8 + hi * 4);
      f32x4 o;
#pragma unroll
      for (int r = 0; r < 4; ++r) o[r] = A[q * 4 + r] + bv[r];
      *(f32x4*)(grow + nt * 32 + q * 8 + hi * 4) = o;
    }
  }
}

template<bool WSPATH>
__global__ __launch_bounds__(512, 2) void mlp_fused(
    const float* __restrict__ x,
    const float* __restrict__ w0f, const float* __restrict__ w1f,
    const float* __restrict__ w2f, const float* __restrict__ w3f,
    const float* __restrict__ b0, const float* __restrict__ b1,
    const float* __restrict__ b2, const float* __restrict__ b3,
    const bf16* __restrict__ wbase,
    float* __restrict__ out)
{
  extern __shared__ char lds[];   // 128 KiB: weight-chunk double buffer only

  const int tid = threadIdx.x;
  const int w = tid >> 6, l = tid & 63;
  const int l31 = l & 31, hi = l >> 5;

  // XCD-chunked swizzle (1024 % 8 == 0 -> bijective): each XCD owns one channel
  const int wg = (blockIdx.x & 7) * 128 + (blockIdx.x >> 3);
  const int ch = wg >> 7;
  const int row0 = (wg & 127) * BM;
  const int myrow = row0 + w * 32 + l31;

  const bf16* w0b = wbase + (size_t)ch * UN * FIN;
  const bf16* w1b = wbase + CH * UN * FIN + (size_t)ch * UN * UN;
  const bf16* w2b = wbase + CH * UN * FIN + CH * UN * UN + (size_t)ch * UN * UN;
  const bf16* w3b = wbase + CH * UN * FIN + 2 * CH * UN * UN + (size_t)ch * FOUT * UN;
  const float* w0c = w0f + (size_t)ch * UN * FIN;
  const float* w1c = w1f + (size_t)ch * UN * UN;
  const float* w2c = w2f + (size_t)ch * UN * UN;
  const float* w3c = w3f + (size_t)ch * FOUT * UN;
  const float* b0c = b0 + ch * UN;
  const float* b1c = b1 + ch * UN;
  const float* b2c = b2 + ch * UN;
  const float* b3c = b3 + ch * FOUT;

  // x -> registers (raw feature order): frag j = fp32[j*16 + hi*8 .. +8)
  bf16x8 X[4];
  {
    const float* xr = x + ((size_t)ch * SEC + myrow) * FIN + hi * 8;
#pragma unroll
    for (int j = 0; j < 4; ++j) X[j] = cvt8(xr + j * 16);
  }

  bf16x8 bankA[32], bankB[32];
  run_hidden<64,  WSPATH>(w0b, w0c, b0c, X,     bankA, lds, tid, l, l31, hi);
  run_hidden<512, WSPATH>(w1b, w1c, b1c, bankA, bankB, lds, tid, l, l31, hi);
  run_hidden<512, WSPATH>(w2b, w2c, b2c, bankB, bankA, lds, tid, l, l31, hi);
  run_final<WSPATH>(w3b, w3c, b3c, bankA,
                    out + ((size_t)ch * SEC + myrow) * FOUT,
                    lds, tid, l, l31, hi);
}

// ---------------------------------------------------------------------------
// Weight pre-swizzle into d_ws. Layout per layer per channel, chunk-major:
//   elem(((c*2+nt)*NKS + j)*64 + l)*8 + e
//     row = (c*2+nt)*32 + (l&31)
//     col = raw k' = j*16+(l>>5)*8+e  for W0 (input = raw x)
//     col = tau(k') for W1/W2/W3 (input = repacked activations), where the
//     kappa^-1 gather for an 8-run is two f32x4 at
//     (j>>1)*32 + (j&1)*16 + (l>>5)*4 and +8.
// ---------------------------------------------------------------------------
__global__ void cvt_weights(const float* __restrict__ w0, const float* __restrict__ w1,
                            const float* __restrict__ w2, const float* __restrict__ w3,
                            bf16* __restrict__ o)
{
  constexpr int G0 = CH * UN * FIN / 8;    // 32768 groups
  constexpr int G1 = CH * UN * UN / 8;     // 262144
  constexpr int G3 = CH * FOUT * UN / 8;   // 32768
  constexpr int total = G0 + 2 * G1 + G3;  // 589824
  for (int t = blockIdx.x * blockDim.x + threadIdx.x; t < total;
       t += gridDim.x * blockDim.x) {
    bf16x8 v;
    if (t < G0) {
      const int ch = t >> 12, r = t & 4095;
      const int l = r & 63, p = r >> 6;      // p 0..63
      const int j = p & 3, tile = p >> 2;    // tile 0..15
      const int row = tile * 32 + (l & 31);
      v = cvt8(w0 + (size_t)ch * UN * FIN + (size_t)row * FIN + j * 16 + (l >> 5) * 8);
    } else if (t < G0 + 2 * G1) {
      const int t1 = t - G0;
      const float* src = (t1 < G1) ? w1 : w2;
      const int t2 = (t1 < G1) ? t1 : t1 - G1;
      const int ch = t2 >> 15, r = t2 & 32767;
      const int l = r & 63, p = r >> 6;      // p 0..511
      const int j = p & 31, tile = p >> 5;   // tile 0..15
      const int row = tile * 32 + (l & 31);
      const int coff = (j >> 1) * 32 + (j & 1) * 16 + (l >> 5) * 4;
      v = cvt8_gap(src + (size_t)ch * UN * UN + (size_t)row * UN + coff);
    } else {
      const int t3 = t - G0 - 2 * G1;
      const int ch = t3 >> 12, r = t3 & 4095;
      const int l = r & 63, p = r >> 6;      // p 0..63
      const int j = p & 31, nt = p >> 5;
      const int row = nt * 32 + (l & 31);
      const int coff = (j >> 1) * 32 + (j & 1) * 16 + (l >> 5) * 4;
      v = cvt8_gap(w3 + (size_t)ch * FOUT * UN + (size_t)row * UN + coff);
    }
    *(bf16x8*)(o + (size_t)t * 8) = v;
  }
}

extern "C" void kernel_launch(void* const* d_in, const int* in_sizes, int n_in,
                              void* d_out, int out_size, void* d_ws, size_t ws_size,
                              hipStream_t stream)
{
  const float* x  = (const float*)d_in[0];
  const float* w0 = (const float*)d_in[1];
  const float* w1 = (const float*)d_in[2];
  const float* w2 = (const float*)d_in[3];
  const float* w3 = (const float*)d_in[4];
  const float* b0 = (const float*)d_in[5];
  const float* b1 = (const float*)d_in[6];
  const float* b2 = (const float*)d_in[7];
  const float* b3 = (const float*)d_in[8];
  float* out = (float*)d_out;

  const int grid = CH * (SEC / BM);            // 1024 blocks
  const size_t wbytes = (size_t)(2 * CH * UN * FIN + 2 * CH * UN * UN) * 2;  // 9437184

  if (ws_size >= wbytes) {
    bf16* wb = (bf16*)d_ws;
    hipLaunchKernelGGL(cvt_weights, dim3(2304), dim3(256), 0, stream, w0, w1, w2, w3, wb);
    hipFuncSetAttribute(reinterpret_cast<const void*>(mlp_fused<true>),
                        hipFuncAttributeMaxDynamicSharedMemorySize, 131072);
    hipLaunchKernelGGL(mlp_fused<true>, dim3(grid), dim3(512), 131072, stream,
                       x, w0, w1, w2, w3, b0, b1, b2, b3, wb, out);
  } else {
    hipFuncSetAttribute(reinterpret_cast<const void*>(mlp_fused<false>),
                        hipFuncAttributeMaxDynamicSharedMemorySize, 131072);
    hipLaunchKernelGGL(mlp_fused<false>, dim3(grid), dim3(512), 131072, stream,
                       x, w0, w1, w2, w3, b0, b1, b2, b3, (const bf16*)nullptr, out);
  }
}

// Round 15
// 392.026 us; speedup vs baseline: 1.0464x; 1.0464x over previous
//
#include <hip/hip_runtime.h>
#include <hip/hip_bf16.h>

#define CH 8
#define SEC 32768
#define FIN 64
#define FOUT 64
#define UN 512
#define BM 128   // 4 waves x 32 rows per wave

typedef __bf16 bf16;
typedef bf16 bf16x8 __attribute__((ext_vector_type(8)));
typedef float f32x4 __attribute__((ext_vector_type(4)));
typedef float f32x16 __attribute__((ext_vector_type(16)));

// async global->LDS, 16B/lane; LDS dest = wave-uniform base + lane*16
__device__ __forceinline__ void gload_lds16(const void* g, void* l) {
  __builtin_amdgcn_global_load_lds(
      (const __attribute__((address_space(1))) void*)g,
      (__attribute__((address_space(3))) void*)l, 16, 0, 0);
}

// 8 consecutive fp32 -> bf16x8
__device__ __forceinline__ bf16x8 cvt8(const float* __restrict__ src) {
  f32x4 u0 = *(const f32x4*)src;
  f32x4 u1 = *(const f32x4*)(src + 4);
  bf16x8 v;
  v[0] = (bf16)u0[0]; v[1] = (bf16)u0[1]; v[2] = (bf16)u0[2]; v[3] = (bf16)u0[3];
  v[4] = (bf16)u1[0]; v[5] = (bf16)u1[1]; v[6] = (bf16)u1[2]; v[7] = (bf16)u1[3];
  return v;
}

// two f32x4 runs at src and src+8 (the kappa^-1 gather) -> bf16x8
__device__ __forceinline__ bf16x8 cvt8_gap(const float* __restrict__ src) {
  f32x4 u0 = *(const f32x4*)src;
  f32x4 u1 = *(const f32x4*)(src + 8);
  bf16x8 v;
  v[0] = (bf16)u0[0]; v[1] = (bf16)u0[1]; v[2] = (bf16)u0[2]; v[3] = (bf16)u0[3];
  v[4] = (bf16)u1[0]; v[5] = (bf16)u1[1]; v[6] = (bf16)u1[2]; v[7] = (bf16)u1[3];
  return v;
}

// ---------------------------------------------------------------------------
// Register-resident MLP (R14 dataflow, PASSED refcheck) at the LEGAL register
// budget: 256 threads (4 waves), __launch_bounds__(256,1) -> 1 wave/SIMD ->
// 512 VGPRs/wave. Banks 2x128 + acc 32 + B 16 + addr ~50 = ~350, no spill.
// Wave owns 32 rows for ALL layers; activations in bf16x8 banks. mfma(W,X)
// keeps the row on the lane; D slot->next-k permutation absorbed into the
// weight pre-swizzle (verified R14). LDS = weight-chunk broadcast only
// (64KB/chunk, double-buffered halves, prefetch before compute).
// ---------------------------------------------------------------------------
template<int K, bool WSPATH>
__device__ __forceinline__ void run_hidden(
    const bf16* __restrict__ wc,    // channel's swizzled layer weights
    const float* __restrict__ wfc,  // raw fp32 fallback
    const float* __restrict__ bias,
    const bf16x8 (&Ain)[K / 16], bf16x8 (&Aout)[32],
    char* __restrict__ lds, int tid, int l, int l31, int hi)
{
  constexpr int NKS = K / 16;

  if constexpr (WSPATH) {
    __syncthreads();   // prior LDS readers done before we overwrite
#pragma unroll
    for (int i = 0; i < 16; ++i)  // 256 thr x 16B x 16 = 64KB (chunk0 / whole w0)
      gload_lds16((const char*)wc + tid * 16 + i * 4096,
                  lds + tid * 16 + i * 4096);
    __syncthreads();
  }

#pragma unroll
  for (int c = 0; c < 8; ++c) {
    const char* wb = lds;
    if constexpr (WSPATH) {
      if constexpr (K == 64) {
        wb = lds + c * 8192 + l * 16;
      } else {
        if (c + 1 < 8) {  // prefetch next chunk into other half
          const char* src = (const char*)wc + (size_t)(c + 1) * 65536;
#pragma unroll
          for (int i = 0; i < 16; ++i)
            gload_lds16(src + tid * 16 + i * 4096,
                        lds + ((c + 1) & 1) * 65536 + tid * 16 + i * 4096);
        }
        wb = lds + (c & 1) * 65536 + l * 16;
      }
    }

    f32x16 acc0, acc1;
#pragma unroll
    for (int r = 0; r < 16; ++r) { acc0[r] = 0.f; acc1[r] = 0.f; }

#pragma unroll
    for (int j = 0; j < NKS; ++j) {
      bf16x8 b0, b1;
      if constexpr (WSPATH) {
        b0 = *(const bf16x8*)(wb + (0 * NKS + j) * 1024);
        b1 = *(const bf16x8*)(wb + (1 * NKS + j) * 1024);
      } else {
        const int r0 = c * 64 + l31;
        if constexpr (K == 64) {
          b0 = cvt8(wfc + (size_t)r0 * K + j * 16 + hi * 8);
          b1 = cvt8(wfc + (size_t)(r0 + 32) * K + j * 16 + hi * 8);
        } else {
          const int coff = (j >> 1) * 32 + (j & 1) * 16 + hi * 4;
          b0 = cvt8_gap(wfc + (size_t)r0 * K + coff);
          b1 = cvt8_gap(wfc + (size_t)(r0 + 32) * K + coff);
        }
      }
      acc0 = __builtin_amdgcn_mfma_f32_32x32x16_bf16(b0, Ain[j], acc0, 0, 0, 0);
      acc1 = __builtin_amdgcn_mfma_f32_32x32x16_bf16(b1, Ain[j], acc1, 0, 0, 0);
    }

    // bias + relu + repack: regs 0..7 -> kstep 2t, regs 8..15 -> kstep 2t+1
#pragma unroll
    for (int nt = 0; nt < 2; ++nt) {
      const f32x16 A = (nt == 0) ? acc0 : acc1;
      float v[16];
#pragma unroll
      for (int q = 0; q < 4; ++q) {
        const f32x4 bv = *(const f32x4*)(bias + c * 64 + nt * 32 + q * 8 + hi * 4);
#pragma unroll
        for (int r = 0; r < 4; ++r) {
          const float t = A[q * 4 + r] + bv[r];
          v[q * 4 + r] = t > 0.f ? t : 0.f;
        }
      }
      bf16x8 p0, p1;
#pragma unroll
      for (int e = 0; e < 8; ++e) { p0[e] = (bf16)v[e]; p1[e] = (bf16)v[8 + e]; }
      Aout[(c * 2 + nt) * 2 + 0] = p0;
      Aout[(c * 2 + nt) * 2 + 1] = p1;
    }

    if constexpr (WSPATH && K != 64) __syncthreads();  // prefetch landed; half free
  }
}

// ---------------------------------------------------------------------------
// Final layer: one 64-feature chunk, K=512, no relu, fp32 store.
// ---------------------------------------------------------------------------
template<bool WSPATH>
__device__ __forceinline__ void run_final(
    const bf16* __restrict__ wc, const float* __restrict__ wfc,
    const float* __restrict__ bias, const bf16x8 (&Ain)[32],
    float* __restrict__ grow,   // out + myrow*FOUT
    char* __restrict__ lds, int tid, int l, int l31, int hi)
{
  if constexpr (WSPATH) {
    __syncthreads();
#pragma unroll
    for (int i = 0; i < 16; ++i)
      gload_lds16((const char*)wc + tid * 16 + i * 4096, lds + tid * 16 + i * 4096);
    __syncthreads();
  }

  f32x16 acc0, acc1;
#pragma unroll
  for (int r = 0; r < 16; ++r) { acc0[r] = 0.f; acc1[r] = 0.f; }

#pragma unroll
  for (int j = 0; j < 32; ++j) {
    bf16x8 b0, b1;
    if constexpr (WSPATH) {
      b0 = *(const bf16x8*)(lds + (j) * 1024 + l * 16);
      b1 = *(const bf16x8*)(lds + (32 + j) * 1024 + l * 16);
    } else {
      const int coff = (j >> 1) * 32 + (j & 1) * 16 + hi * 4;
      b0 = cvt8_gap(wfc + (size_t)l31 * UN + coff);
      b1 = cvt8_gap(wfc + (size_t)(32 + l31) * UN + coff);
    }
    acc0 = __builtin_amdgcn_mfma_f32_32x32x16_bf16(b0, Ain[j], acc0, 0, 0, 0);
    acc1 = __builtin_amdgcn_mfma_f32_32x32x16_bf16(b1, Ain[j], acc1, 0, 0, 0);
  }

#pragma unroll
  for (int nt = 0; nt < 2; ++nt) {
    const f32x16 A = (nt == 0) ? acc0 : acc1;
#pragma unroll
    for (int q = 0; q < 4; ++q) {
      const f32x4 bv = *(const f32x4*)(bias + nt * 32 + q * 8 + hi * 4);
      f32x4 o;
#pragma unroll
      for (int r = 0; r < 4; ++r) o[r] = A[q * 4 + r] + bv[r];
      *(f32x4*)(grow + nt * 32 + q * 8 + hi * 4) = o;
    }
  }
}

template<bool WSPATH>
__global__ __launch_bounds__(256, 1) void mlp_fused(
    const float* __restrict__ x,
    const float* __restrict__ w0f, const float* __restrict__ w1f,
    const float* __restrict__ w2f, const float* __restrict__ w3f,
    const float* __restrict__ b0, const float* __restrict__ b1,
    const float* __restrict__ b2, const float* __restrict__ b3,
    const bf16* __restrict__ wbase,
    float* __restrict__ out)
{
  extern __shared__ char lds[];   // 128 KiB: weight-chunk double buffer only

  const int tid = threadIdx.x;
  const int w = tid >> 6, l = tid & 63;
  const int l31 = l & 31, hi = l >> 5;

  // XCD-chunked swizzle (2048 % 8 == 0 -> bijective): each XCD owns one channel
  const int wg = (blockIdx.x & 7) * 256 + (blockIdx.x >> 3);
  const int ch = wg >> 8;
  const int row0 = (wg & 255) * BM;
  const int myrow = row0 + w * 32 + l31;

  const bf16* w0b = wbase + (size_t)ch * UN * FIN;
  const bf16* w1b = wbase + CH * UN * FIN + (size_t)ch * UN * UN;
  const bf16* w2b = wbase + CH * UN * FIN + CH * UN * UN + (size_t)ch * UN * UN;
  const bf16* w3b = wbase + CH * UN * FIN + 2 * CH * UN * UN + (size_t)ch * FOUT * UN;
  const float* w0c = w0f + (size_t)ch * UN * FIN;
  const float* w1c = w1f + (size_t)ch * UN * UN;
  const float* w2c = w2f + (size_t)ch * UN * UN;
  const float* w3c = w3f + (size_t)ch * FOUT * UN;
  const float* b0c = b0 + ch * UN;
  const float* b1c = b1 + ch * UN;
  const float* b2c = b2 + ch * UN;
  const float* b3c = b3 + ch * FOUT;

  // x -> registers (raw feature order): frag j = fp32[j*16 + hi*8 .. +8)
  bf16x8 X[4];
  {
    const float* xr = x + ((size_t)ch * SEC + myrow) * FIN + hi * 8;
#pragma unroll
    for (int j = 0; j < 4; ++j) X[j] = cvt8(xr + j * 16);
  }

  bf16x8 bankA[32], bankB[32];
  run_hidden<64,  WSPATH>(w0b, w0c, b0c, X,     bankA, lds, tid, l, l31, hi);
  run_hidden<512, WSPATH>(w1b, w1c, b1c, bankA, bankB, lds, tid, l, l31, hi);
  run_hidden<512, WSPATH>(w2b, w2c, b2c, bankB, bankA, lds, tid, l, l31, hi);
  run_final<WSPATH>(w3b, w3c, b3c, bankA,
                    out + ((size_t)ch * SEC + myrow) * FOUT,
                    lds, tid, l, l31, hi);
}

// ---------------------------------------------------------------------------
// Weight pre-swizzle into d_ws (UNCHANGED from R14 -- refcheck-verified).
// Per layer per channel, chunk-major: elem(((tile)*NKS + j)*64 + l)*8 + e
//   row = tile*32 + (l&31); col = raw k for W0, tau(k) gather for W1/2/3
//   via two f32x4 at (j>>1)*32 + (j&1)*16 + (l>>5)*4 and +8.
// ---------------------------------------------------------------------------
__global__ void cvt_weights(const float* __restrict__ w0, const float* __restrict__ w1,
                            const float* __restrict__ w2, const float* __restrict__ w3,
                            bf16* __restrict__ o)
{
  constexpr int G0 = CH * UN * FIN / 8;    // 32768 groups
  constexpr int G1 = CH * UN * UN / 8;     // 262144
  constexpr int G3 = CH * FOUT * UN / 8;   // 32768
  constexpr int total = G0 + 2 * G1 + G3;  // 589824
  for (int t = blockIdx.x * blockDim.x + threadIdx.x; t < total;
       t += gridDim.x * blockDim.x) {
    bf16x8 v;
    if (t < G0) {
      const int ch = t >> 12, r = t & 4095;
      const int l = r & 63, p = r >> 6;      // p 0..63
      const int j = p & 3, tile = p >> 2;    // tile 0..15
      const int row = tile * 32 + (l & 31);
      v = cvt8(w0 + (size_t)ch * UN * FIN + (size_t)row * FIN + j * 16 + (l >> 5) * 8);
    } else if (t < G0 + 2 * G1) {
      const int t1 = t - G0;
      const float* src = (t1 < G1) ? w1 : w2;
      const int t2 = (t1 < G1) ? t1 : t1 - G1;
      const int ch = t2 >> 15, r = t2 & 32767;
      const int l = r & 63, p = r >> 6;      // p 0..511
      const int j = p & 31, tile = p >> 5;   // tile 0..15
      const int row = tile * 32 + (l & 31);
      const int coff = (j >> 1) * 32 + (j & 1) * 16 + (l >> 5) * 4;
      v = cvt8_gap(src + (size_t)ch * UN * UN + (size_t)row * UN + coff);
    } else {
      const int t3 = t - G0 - 2 * G1;
      const int ch = t3 >> 12, r = t3 & 4095;
      const int l = r & 63, p = r >> 6;      // p 0..63
      const int j = p & 31, nt = p >> 5;
      const int row = nt * 32 + (l & 31);
      const int coff = (j >> 1) * 32 + (j & 1) * 16 + (l >> 5) * 4;
      v = cvt8_gap(w3 + (size_t)ch * FOUT * UN + (size_t)row * UN + coff);
    }
    *(bf16x8*)(o + (size_t)t * 8) = v;
  }
}

extern "C" void kernel_launch(void* const* d_in, const int* in_sizes, int n_in,
                              void* d_out, int out_size, void* d_ws, size_t ws_size,
                              hipStream_t stream)
{
  const float* x  = (const float*)d_in[0];
  const float* w0 = (const float*)d_in[1];
  const float* w1 = (const float*)d_in[2];
  const float* w2 = (const float*)d_in[3];
  const float* w3 = (const float*)d_in[4];
  const float* b0 = (const float*)d_in[5];
  const float* b1 = (const float*)d_in[6];
  const float* b2 = (const float*)d_in[7];
  const float* b3 = (const float*)d_in[8];
  float* out = (float*)d_out;

  const int grid = CH * (SEC / BM);            // 2048 blocks
  const size_t wbytes = (size_t)(2 * CH * UN * FIN + 2 * CH * UN * UN) * 2;  // 9437184

  if (ws_size >= wbytes) {
    bf16* wb = (bf16*)d_ws;
    hipLaunchKernelGGL(cvt_weights, dim3(2304), dim3(256), 0, stream, w0, w1, w2, w3, wb);
    hipFuncSetAttribute(reinterpret_cast<const void*>(mlp_fused<true>),
                        hipFuncAttributeMaxDynamicSharedMemorySize, 131072);
    hipLaunchKernelGGL(mlp_fused<true>, dim3(grid), dim3(256), 131072, stream,
                       x, w0, w1, w2, w3, b0, b1, b2, b3, wb, out);
  } else {
    hipFuncSetAttribute(reinterpret_cast<const void*>(mlp_fused<false>),
                        hipFuncAttributeMaxDynamicSharedMemorySize, 131072);
    hipLaunchKernelGGL(mlp_fused<false>, dim3(grid), dim3(256), 131072, stream,
                       x, w0, w1, w2, w3, b0, b1, b2, b3, (const bf16*)nullptr, out);
  }
}

// Round 16
// 358.577 us; speedup vs baseline: 1.1440x; 1.0933x over previous
//
#include <hip/hip_runtime.h>
#include <hip/hip_bf16.h>

#define CH 8
#define SEC 32768
#define FIN 64
#define FOUT 64
#define UN 512
#define BM 128   // 4 waves x 32 rows per wave

typedef __bf16 bf16;
typedef bf16 bf16x8 __attribute__((ext_vector_type(8)));
typedef float f32x4 __attribute__((ext_vector_type(4)));
typedef float f32x16 __attribute__((ext_vector_type(16)));

// async global->LDS, 16B/lane; LDS dest = wave-uniform base + lane*16
__device__ __forceinline__ void gload_lds16(const void* g, void* l) {
  __builtin_amdgcn_global_load_lds(
      (const __attribute__((address_space(1))) void*)g,
      (__attribute__((address_space(3))) void*)l, 16, 0, 0);
}

// 8 consecutive fp32 -> bf16x8
__device__ __forceinline__ bf16x8 cvt8(const float* __restrict__ src) {
  f32x4 u0 = *(const f32x4*)src;
  f32x4 u1 = *(const f32x4*)(src + 4);
  bf16x8 v;
  v[0] = (bf16)u0[0]; v[1] = (bf16)u0[1]; v[2] = (bf16)u0[2]; v[3] = (bf16)u0[3];
  v[4] = (bf16)u1[0]; v[5] = (bf16)u1[1]; v[6] = (bf16)u1[2]; v[7] = (bf16)u1[3];
  return v;
}

// two f32x4 runs at src and src+8 (the kappa^-1 gather) -> bf16x8
__device__ __forceinline__ bf16x8 cvt8_gap(const float* __restrict__ src) {
  f32x4 u0 = *(const f32x4*)src;
  f32x4 u1 = *(const f32x4*)(src + 8);
  bf16x8 v;
  v[0] = (bf16)u0[0]; v[1] = (bf16)u0[1]; v[2] = (bf16)u0[2]; v[3] = (bf16)u0[3];
  v[4] = (bf16)u1[0]; v[5] = (bf16)u1[1]; v[6] = (bf16)u1[2]; v[7] = (bf16)u1[3];
  return v;
}

// ---------------------------------------------------------------------------
// Register-resident MLP (R14/R15 dataflow, refcheck-verified) with an
// explicit DEPTH-4 B-REGISTER RING to overlap the LDS-read pipe with the
// MFMA pipe at 1 wave/SIMD: 8 ds_reads always in flight; each j-step's 2
// MFMAs are followed by re-issuing the slot's loads for j+4 (WAR-safe:
// in-order issue reads operands before the ds_read writes back).
// Budget at __launch_bounds__(256,1): banks 256 + acc 32 + ring 32 + addr
// ~40 = ~360 of 512 VGPRs, no spill.
// ---------------------------------------------------------------------------
template<int K, bool WSPATH>
__device__ __forceinline__ void run_hidden(
    const bf16* __restrict__ wc,    // channel's swizzled layer weights
    const float* __restrict__ wfc,  // raw fp32 fallback
    const float* __restrict__ bias,
    const bf16x8 (&Ain)[K / 16], bf16x8 (&Aout)[32],
    char* __restrict__ lds, int tid, int l, int l31, int hi)
{
  constexpr int NKS = K / 16;

  if constexpr (WSPATH) {
    __syncthreads();   // prior LDS readers done before we overwrite
#pragma unroll
    for (int i = 0; i < 16; ++i)  // 256 thr x 16B x 16 = 64KB (chunk0 / whole w0)
      gload_lds16((const char*)wc + tid * 16 + i * 4096,
                  lds + tid * 16 + i * 4096);
    __syncthreads();
  }

#pragma unroll
  for (int c = 0; c < 8; ++c) {
    const char* wb = lds;
    if constexpr (WSPATH) {
      if constexpr (K == 64) {
        wb = lds + c * 8192 + l * 16;
      } else {
        if (c + 1 < 8) {  // prefetch next chunk into other half (vmcnt ops)
          const char* src = (const char*)wc + (size_t)(c + 1) * 65536;
#pragma unroll
          for (int i = 0; i < 16; ++i)
            gload_lds16(src + tid * 16 + i * 4096,
                        lds + ((c + 1) & 1) * 65536 + tid * 16 + i * 4096);
        }
        wb = lds + (c & 1) * 65536 + l * 16;
      }
    }

    f32x16 acc0, acc1;
#pragma unroll
    for (int r = 0; r < 16; ++r) { acc0[r] = 0.f; acc1[r] = 0.f; }

    if constexpr (WSPATH && K != 64) {
      // ---- depth-4 B-register ring over the 32 j-steps ----
      bf16x8 Bs[4][2];
#pragma unroll
      for (int s = 0; s < 4; ++s) {
        Bs[s][0] = *(const bf16x8*)(wb + s * 1024);
        Bs[s][1] = *(const bf16x8*)(wb + 32768 + s * 1024);
      }
#pragma unroll
      for (int j = 0; j < NKS; ++j) {
        acc0 = __builtin_amdgcn_mfma_f32_32x32x16_bf16(Bs[j & 3][0], Ain[j], acc0, 0, 0, 0);
        acc1 = __builtin_amdgcn_mfma_f32_32x32x16_bf16(Bs[j & 3][1], Ain[j], acc1, 0, 0, 0);
        if (j + 4 < NKS) {
          Bs[j & 3][0] = *(const bf16x8*)(wb + (j + 4) * 1024);
          Bs[j & 3][1] = *(const bf16x8*)(wb + 32768 + (j + 4) * 1024);
        }
      }
    } else {
#pragma unroll
      for (int j = 0; j < NKS; ++j) {
        bf16x8 b0, b1;
        if constexpr (WSPATH) {
          b0 = *(const bf16x8*)(wb + (0 * NKS + j) * 1024);
          b1 = *(const bf16x8*)(wb + (1 * NKS + j) * 1024);
        } else {
          const int r0 = c * 64 + l31;
          if constexpr (K == 64) {
            b0 = cvt8(wfc + (size_t)r0 * K + j * 16 + hi * 8);
            b1 = cvt8(wfc + (size_t)(r0 + 32) * K + j * 16 + hi * 8);
          } else {
            const int coff = (j >> 1) * 32 + (j & 1) * 16 + hi * 4;
            b0 = cvt8_gap(wfc + (size_t)r0 * K + coff);
            b1 = cvt8_gap(wfc + (size_t)(r0 + 32) * K + coff);
          }
        }
        acc0 = __builtin_amdgcn_mfma_f32_32x32x16_bf16(b0, Ain[j], acc0, 0, 0, 0);
        acc1 = __builtin_amdgcn_mfma_f32_32x32x16_bf16(b1, Ain[j], acc1, 0, 0, 0);
      }
    }

    // bias + relu + repack: regs 0..7 -> kstep 2t, regs 8..15 -> kstep 2t+1
#pragma unroll
    for (int nt = 0; nt < 2; ++nt) {
      const f32x16 A = (nt == 0) ? acc0 : acc1;
      float v[16];
#pragma unroll
      for (int q = 0; q < 4; ++q) {
        const f32x4 bv = *(const f32x4*)(bias + c * 64 + nt * 32 + q * 8 + hi * 4);
#pragma unroll
        for (int r = 0; r < 4; ++r) {
          const float t = A[q * 4 + r] + bv[r];
          v[q * 4 + r] = t > 0.f ? t : 0.f;
        }
      }
      bf16x8 p0, p1;
#pragma unroll
      for (int e = 0; e < 8; ++e) { p0[e] = (bf16)v[e]; p1[e] = (bf16)v[8 + e]; }
      Aout[(c * 2 + nt) * 2 + 0] = p0;
      Aout[(c * 2 + nt) * 2 + 1] = p1;
    }

    if constexpr (WSPATH && K != 64) __syncthreads();  // prefetch landed; half free
  }
}

// ---------------------------------------------------------------------------
// Final layer: one 64-feature chunk, K=512, no relu, fp32 store. Same ring.
// ---------------------------------------------------------------------------
template<bool WSPATH>
__device__ __forceinline__ void run_final(
    const bf16* __restrict__ wc, const float* __restrict__ wfc,
    const float* __restrict__ bias, const bf16x8 (&Ain)[32],
    float* __restrict__ grow,   // out + myrow*FOUT
    char* __restrict__ lds, int tid, int l, int l31, int hi)
{
  if constexpr (WSPATH) {
    __syncthreads();
#pragma unroll
    for (int i = 0; i < 16; ++i)
      gload_lds16((const char*)wc + tid * 16 + i * 4096, lds + tid * 16 + i * 4096);
    __syncthreads();
  }

  f32x16 acc0, acc1;
#pragma unroll
  for (int r = 0; r < 16; ++r) { acc0[r] = 0.f; acc1[r] = 0.f; }

  if constexpr (WSPATH) {
    const char* wb = lds + l * 16;
    bf16x8 Bs[4][2];
#pragma unroll
    for (int s = 0; s < 4; ++s) {
      Bs[s][0] = *(const bf16x8*)(wb + s * 1024);
      Bs[s][1] = *(const bf16x8*)(wb + 32768 + s * 1024);
    }
#pragma unroll
    for (int j = 0; j < 32; ++j) {
      acc0 = __builtin_amdgcn_mfma_f32_32x32x16_bf16(Bs[j & 3][0], Ain[j], acc0, 0, 0, 0);
      acc1 = __builtin_amdgcn_mfma_f32_32x32x16_bf16(Bs[j & 3][1], Ain[j], acc1, 0, 0, 0);
      if (j + 4 < 32) {
        Bs[j & 3][0] = *(const bf16x8*)(wb + (j + 4) * 1024);
        Bs[j & 3][1] = *(const bf16x8*)(wb + 32768 + (j + 4) * 1024);
      }
    }
  } else {
#pragma unroll
    for (int j = 0; j < 32; ++j) {
      const int coff = (j >> 1) * 32 + (j & 1) * 16 + hi * 4;
      const bf16x8 b0 = cvt8_gap(wfc + (size_t)l31 * UN + coff);
      const bf16x8 b1 = cvt8_gap(wfc + (size_t)(32 + l31) * UN + coff);
      acc0 = __builtin_amdgcn_mfma_f32_32x32x16_bf16(b0, Ain[j], acc0, 0, 0, 0);
      acc1 = __builtin_amdgcn_mfma_f32_32x32x16_bf16(b1, Ain[j], acc1, 0, 0, 0);
    }
  }

#pragma unroll
  for (int nt = 0; nt < 2; ++nt) {
    const f32x16 A = (nt == 0) ? acc0 : acc1;
#pragma unroll
    for (int q = 0; q < 4; ++q) {
      const f32x4 bv = *(const f32x4*)(bias + nt * 32 + q * 8 + hi * 4);
      f32x4 o;
#pragma unroll
      for (int r = 0; r < 4; ++r) o[r] = A[q * 4 + r] + bv[r];
      *(f32x4*)(grow + nt * 32 + q * 8 + hi * 4) = o;
    }
  }
}

template<bool WSPATH>
__global__ __launch_bounds__(256, 1) void mlp_fused(
    const float* __restrict__ x,
    const float* __restrict__ w0f, const float* __restrict__ w1f,
    const float* __restrict__ w2f, const float* __restrict__ w3f,
    const float* __restrict__ b0, const float* __restrict__ b1,
    const float* __restrict__ b2, const float* __restrict__ b3,
    const bf16* __restrict__ wbase,
    float* __restrict__ out)
{
  extern __shared__ char lds[];   // 128 KiB: weight-chunk double buffer only

  const int tid = threadIdx.x;
  const int w = tid >> 6, l = tid & 63;
  const int l31 = l & 31, hi = l >> 5;

  // XCD-chunked swizzle (2048 % 8 == 0 -> bijective): each XCD owns one channel
  const int wg = (blockIdx.x & 7) * 256 + (blockIdx.x >> 3);
  const int ch = wg >> 8;
  const int row0 = (wg & 255) * BM;
  const int myrow = row0 + w * 32 + l31;

  const bf16* w0b = wbase + (size_t)ch * UN * FIN;
  const bf16* w1b = wbase + CH * UN * FIN + (size_t)ch * UN * UN;
  const bf16* w2b = wbase + CH * UN * FIN + CH * UN * UN + (size_t)ch * UN * UN;
  const bf16* w3b = wbase + CH * UN * FIN + 2 * CH * UN * UN + (size_t)ch * FOUT * UN;
  const float* w0c = w0f + (size_t)ch * UN * FIN;
  const float* w1c = w1f + (size_t)ch * UN * UN;
  const float* w2c = w2f + (size_t)ch * UN * UN;
  const float* w3c = w3f + (size_t)ch * FOUT * UN;
  const float* b0c = b0 + ch * UN;
  const float* b1c = b1 + ch * UN;
  const float* b2c = b2 + ch * UN;
  const float* b3c = b3 + ch * FOUT;

  // x -> registers (raw feature order): frag j = fp32[j*16 + hi*8 .. +8)
  bf16x8 X[4];
  {
    const float* xr = x + ((size_t)ch * SEC + myrow) * FIN + hi * 8;
#pragma unroll
    for (int j = 0; j < 4; ++j) X[j] = cvt8(xr + j * 16);
  }

  bf16x8 bankA[32], bankB[32];
  run_hidden<64,  WSPATH>(w0b, w0c, b0c, X,     bankA, lds, tid, l, l31, hi);
  run_hidden<512, WSPATH>(w1b, w1c, b1c, bankA, bankB, lds, tid, l, l31, hi);
  run_hidden<512, WSPATH>(w2b, w2c, b2c, bankB, bankA, lds, tid, l, l31, hi);
  run_final<WSPATH>(w3b, w3c, b3c, bankA,
                    out + ((size_t)ch * SEC + myrow) * FOUT,
                    lds, tid, l, l31, hi);
}

// ---------------------------------------------------------------------------
// Weight pre-swizzle into d_ws (UNCHANGED from R14/R15 -- refcheck-verified).
// ---------------------------------------------------------------------------
__global__ void cvt_weights(const float* __restrict__ w0, const float* __restrict__ w1,
                            const float* __restrict__ w2, const float* __restrict__ w3,
                            bf16* __restrict__ o)
{
  constexpr int G0 = CH * UN * FIN / 8;    // 32768 groups
  constexpr int G1 = CH * UN * UN / 8;     // 262144
  constexpr int G3 = CH * FOUT * UN / 8;   // 32768
  constexpr int total = G0 + 2 * G1 + G3;  // 589824
  for (int t = blockIdx.x * blockDim.x + threadIdx.x; t < total;
       t += gridDim.x * blockDim.x) {
    bf16x8 v;
    if (t < G0) {
      const int ch = t >> 12, r = t & 4095;
      const int l = r & 63, p = r >> 6;      // p 0..63
      const int j = p & 3, tile = p >> 2;    // tile 0..15
      const int row = tile * 32 + (l & 31);
      v = cvt8(w0 + (size_t)ch * UN * FIN + (size_t)row * FIN + j * 16 + (l >> 5) * 8);
    } else if (t < G0 + 2 * G1) {
      const int t1 = t - G0;
      const float* src = (t1 < G1) ? w1 : w2;
      const int t2 = (t1 < G1) ? t1 : t1 - G1;
      const int ch = t2 >> 15, r = t2 & 32767;
      const int l = r & 63, p = r >> 6;      // p 0..511
      const int j = p & 31, tile = p >> 5;   // tile 0..15
      const int row = tile * 32 + (l & 31);
      const int coff = (j >> 1) * 32 + (j & 1) * 16 + (l >> 5) * 4;
      v = cvt8_gap(src + (size_t)ch * UN * UN + (size_t)row * UN + coff);
    } else {
      const int t3 = t - G0 - 2 * G1;
      const int ch = t3 >> 12, r = t3 & 4095;
      const int l = r & 63, p = r >> 6;      // p 0..63
      const int j = p & 31, nt = p >> 5;
      const int row = nt * 32 + (l & 31);
      const int coff = (j >> 1) * 32 + (j & 1) * 16 + (l >> 5) * 4;
      v = cvt8_gap(w3 + (size_t)ch * FOUT * UN + (size_t)row * UN + coff);
    }
    *(bf16x8*)(o + (size_t)t * 8) = v;
  }
}

extern "C" void kernel_launch(void* const* d_in, const int* in_sizes, int n_in,
                              void* d_out, int out_size, void* d_ws, size_t ws_size,
                              hipStream_t stream)
{
  const float* x  = (const float*)d_in[0];
  const float* w0 = (const float*)d_in[1];
  const float* w1 = (const float*)d_in[2];
  const float* w2 = (const float*)d_in[3];
  const float* w3 = (const float*)d_in[4];
  const float* b0 = (const float*)d_in[5];
  const float* b1 = (const float*)d_in[6];
  const float* b2 = (const float*)d_in[7];
  const float* b3 = (const float*)d_in[8];
  float* out = (float*)d_out;

  const int grid = CH * (SEC / BM);            // 2048 blocks
  const size_t wbytes = (size_t)(2 * CH * UN * FIN + 2 * CH * UN * UN) * 2;  // 9437184

  if (ws_size >= wbytes) {
    bf16* wb = (bf16*)d_ws;
    hipLaunchKernelGGL(cvt_weights, dim3(2304), dim3(256), 0, stream, w0, w1, w2, w3, wb);
    hipFuncSetAttribute(reinterpret_cast<const void*>(mlp_fused<true>),
                        hipFuncAttributeMaxDynamicSharedMemorySize, 131072);
    hipLaunchKernelGGL(mlp_fused<true>, dim3(grid), dim3(256), 131072, stream,
                       x, w0, w1, w2, w3, b0, b1, b2, b3, wb, out);
  } else {
    hipFuncSetAttribute(reinterpret_cast<const void*>(mlp_fused<false>),
                        hipFuncAttributeMaxDynamicSharedMemorySize, 131072);
    hipLaunchKernelGGL(mlp_fused<false>, dim3(grid), dim3(256), 131072, stream,
                       x, w0, w1, w2, w3, b0, b1, b2, b3, (const bf16*)nullptr, out);
  }
}